// Round 12
// baseline (94.241 us; speedup 1.0000x reference)
//
#include <hip/hip_runtime.h>

#define N_NODES 512
#define C_CH    128
#define S_SPEC  10
#define KT      50
#define NT      11

typedef _Float16 h8 __attribute__((ext_vector_type(8)));
typedef float f32x4 __attribute__((ext_vector_type(4)));

// K layout: 50 tiles x 32 slots; tile = 4 octets (one per lane-group g).
// Octet = (offA, offB, j0): slot i computes x[offA]*x[offB]*x[j0+i], j0 in {0,8}.
// N cols (o-major): nt 0..6 = k3, 7..9 = k2, 10 = k1; col = o (0..15).
__device__ h8 g_Bf[KT * NT * 64];   // B pre-swizzled to MFMA B-frag order [kt][nt][lane]
__device__ h8 g_Wf[128 * 64];       // wlin as A-frags: [mt*16+ks][lane], K-expanded (ir,cc)

__device__ __forceinline__ int fc_of(int kt)  { return kt < 43 ? 7 : (kt < 49 ? 3 : 1); }
__device__ __forceinline__ int ntb_of(int kt) { return kt < 43 ? 0 : (kt < 49 ? 7 : 10); }

__device__ __forceinline__ void o_to_iri(int o, int& ir, int& i) {
  if (o >= 9)      { ir = 3; i = o - 9; }
  else if (o >= 4) { ir = 2; i = o - 4; }
  else if (o >= 1) { ir = 1; i = o - 1; }
  else             { ir = 0; i = 0; }
}

__device__ int octet_desc(int Q) {
  if (Q < 172) {                     // order-3
    int q = Q;
    for (int a = 0; a < 16; ++a)
      for (int b = a; b < 16; ++b) {
        int no = (b < 8) ? 2 : 1;
        if (q < no) {
          int jb = (no == 1) ? 1 : q;          // b<8: q0->j0=0,q1->j0=8; b>=8: j0=8
          return a | (b << 5) | (jb << 10);
        }
        q -= no;
      }
  } else if (Q < 196) {              // order-2
    int q = Q - 172;
    for (int a = 0; a < 16; ++a) {
      int no = (a < 8) ? 2 : 1;
      if (q < no) {
        int jb = (no == 1) ? 1 : q;
        return a | (16 << 5) | (jb << 10);
      }
      q -= no;
    }
  } else if (Q < 198) {              // order-1
    return 16 | (16 << 5) | ((Q - 196) << 10);
  }
  return 17 | (17 << 5);             // pad (zero column)
}

// ---- merged build: blocks 0..319 build B fragments, 320..447 build W fragments ----
__global__ void build_all(const float* __restrict__ u1_0, const float* __restrict__ u1_1,
                          const float* __restrict__ u1_2, const float* __restrict__ u1_3,
                          const float* __restrict__ u2_0, const float* __restrict__ u2_1,
                          const float* __restrict__ u2_2, const float* __restrict__ u2_3,
                          const float* __restrict__ u3_0, const float* __restrict__ u3_1,
                          const float* __restrict__ u3_2, const float* __restrict__ u3_3,
                          const float* __restrict__ wlin) {
  const int bid = blockIdx.x;
  const int dis[4] = {1, 3, 5, 7};
  if (bid < 320) {
    int kt, nt;
    if (bid < 301)      { kt = bid / 7; nt = bid % 7; }
    else if (bid < 319) { int e = bid - 301; kt = 43 + e / 3; nt = 7 + e % 3; }
    else                { kt = 49; nt = 10; }

    const int l = threadIdx.x;
    const int o = l & 15;
    int ir, ii; o_to_iri(o, ir, ii);
    const int di = dis[ir];
    const float* u1s[4] = {u1_0, u1_1, u1_2, u1_3};
    const float* u2s[4] = {u2_0, u2_1, u2_2, u2_3};
    const float* u3s[4] = {u3_0, u3_1, u3_2, u3_3};

    const int rt = octet_desc(kt * 4 + (l >> 4));
    const int oA = rt & 31, oB = (rt >> 5) & 31, j0 = ((rt >> 10) & 1) * 8;

    h8 v;
#pragma unroll
    for (int i = 0; i < 8; ++i) {
      const int j = j0 + i;
      float val = 0.f;
      if (oA < 16 && oB < 16) {              // order-3, canonical a<=b<=j
        if (j >= oB) {
          const float* u = u3s[ir];
          int a = oA, b = oB;
          int P[6][3] = {{a,b,j},{a,j,b},{b,a,j},{b,j,a},{j,a,b},{j,b,a}};
          for (int p = 0; p < 6; ++p) {
            bool dup = false;
            for (int r = 0; r < p; ++r)
              if (P[r][0] == P[p][0] && P[r][1] == P[p][1] && P[r][2] == P[p][2]) { dup = true; break; }
            if (!dup)
              val += u[(((P[p][0] * 16 + P[p][1]) * 16 + P[p][2]) * 7 + nt) * di + ii];
          }
        }
      } else if (oA < 16 && oB == 16) {      // order-2 (oA <= j)
        if (j >= oA) {
          const int k2 = nt - 7;
          const float* u = u2s[ir];
          val = u[((oA * 16 + j) * 3 + k2) * di + ii];
          if (j != oA) val += u[((j * 16 + oA) * 3 + k2) * di + ii];
        }
      } else if (oA == 16) {                 // order-1
        val = u1s[ir][j * di + ii];
      }
      v[i] = (_Float16)val;
    }
    g_Bf[((size_t)kt * NT + nt) * 64 + l] = v;
  } else {
    // wlin -> fp16 A-frags over expanded K = (ir*128+cc), scaled by 1/sqrt(128)
    const int id = (bid - 320) * 64 + threadIdx.x;   // 8192 total
    const int l = id & 63, ks = (id >> 6) & 15, mt = id >> 10;
    const int f = mt * 16 + (l & 15);
    const float inv = 0.08838834764831845f;
    h8 v;
#pragma unroll
    for (int i = 0; i < 8; ++i) {
      const int k = ks * 32 + (l >> 4) * 8 + i;
      const int ir = k >> 7, cc = k & 127;
      v[i] = (_Float16)(wlin[((size_t)ir * C_CH + cc) * C_CH + f] * inv);
    }
    g_Wf[(mt * 16 + ks) * 64 + l] = v;
  }
}

// ---------------- main kernel: 2 nodes/block, K-split over blockIdx.y, ws partials ----
// NOTE: no min-waves in __launch_bounds__ (R1/R4/R8 spilled when capped).
// LDS = 57.3 + 18.4 + 0.8 = 76.6 KB -> 2 blocks/CU -> 4 waves/SIMD with K-split grid.

#define MFMA16(A, B, C) __builtin_amdgcn_mfma_f32_16x16x32_f16(A, B, C, 0, 0, 0)

__global__ __launch_bounds__(512, 1) void eqp_mm(
    const float* __restrict__ x, const int* __restrict__ specie,
    const float* __restrict__ w1, const float* __restrict__ w2,
    const float* __restrict__ w3, float* __restrict__ ws, int nsp) {
  __shared__ __align__(16) char bs[2][28 * 1024];   // B chunk double buffer (4 tiles/chunk)
  __shared__ float xT[2][128][18];                  // cols 0..15 x, 16 = 1, 17 = 0
  __shared__ int rtab[KT * 4];

  const int t = threadIdx.x;
  const int l = t & 63;
  const int w = t >> 6;
  const int g = l >> 4;
  const int n0 = blockIdx.x * 2;
  const int ksp = blockIdx.y;          // K part: 0 -> tiles 0..24, 1 -> 25..49 (if nsp==2)

  {  // stage xT + rtab
    const int p = t >> 8, c = (t >> 1) & 127, half = t & 1;
    const float* xp = x + ((size_t)(n0 + p) * C_CH + c) * 16 + half * 8;
    const float4 v0 = *(const float4*)xp, v1 = *(const float4*)(xp + 4);
    float* row = &xT[p][c][half * 8];
    row[0] = v0.x; row[1] = v0.y; row[2] = v0.z; row[3] = v0.w;
    row[4] = v1.x; row[5] = v1.y; row[6] = v1.z; row[7] = v1.w;
    if (half == 1) { xT[p][c][16] = 1.f; xT[p][c][17] = 0.f; }
    if (t < KT * 4) rtab[t] = octet_desc(t);
  }

  const int ch = w * 16 + (l & 15);
  const int s0 = specie[n0], s1 = specie[n0 + 1];

  // pre-convert this lane's channel rows to packed fp16 (RTE) for pk-mul production
  auto packh = [](float4 u, float4 v) {
    h8 r;
    r[0] = (_Float16)u.x; r[1] = (_Float16)u.y; r[2] = (_Float16)u.z; r[3] = (_Float16)u.w;
    r[4] = (_Float16)v.x; r[5] = (_Float16)v.y; r[6] = (_Float16)v.z; r[7] = (_Float16)v.w;
    return r;
  };
  h8 xh0l, xh0h, xh1l, xh1h;
  {
    const float4* p0 = (const float4*)(x + ((size_t)n0 * C_CH + ch) * 16);
    xh0l = packh(p0[0], p0[1]); xh0h = packh(p0[2], p0[3]);
    const float4* p1 = (const float4*)(x + ((size_t)(n0 + 1) * C_CH + ch) * 16);
    xh1l = packh(p1[0], p1[1]); xh1h = packh(p1[2], p1[3]);
  }

  f32x4 acc[2][NT];
#pragma unroll
  for (int p = 0; p < 2; ++p)
#pragma unroll
    for (int i = 0; i < NT; ++i) acc[p][i] = (f32x4){0.f, 0.f, 0.f, 0.f};

  const int T0   = (nsp == 2) ? ksp * 25 : 0;
  const int tEnd = (nsp == 2) ? T0 + 25 : KT;
  const int nck  = (tEnd - T0 + 3) / 4;

  h8 tv[4]; int dst[4];

  auto issue = [&](int cs) {
    int nf = 0;
#pragma unroll
    for (int tt = 0; tt < 4; ++tt) if (cs + tt < tEnd) nf += fc_of(cs + tt);
#pragma unroll
    for (int slot = 0; slot < 4; ++slot) {
      const int fi = slot * 8 + w;
      const bool ok = fi < nf;
      int kt = cs, rem = fi;
      if (ok) { while (rem >= fc_of(kt)) { rem -= fc_of(kt); ++kt; } }
      dst[slot] = ok ? fi : -1;
      if (ok) tv[slot] = g_Bf[((size_t)kt * NT + (ntb_of(kt) + rem)) * 64 + l];
    }
  };
  auto wr = [&](char* buf) {
#pragma unroll
    for (int slot = 0; slot < 4; ++slot)
      if (dst[slot] >= 0) *(h8*)&buf[(size_t)dst[slot] * 1024 + (size_t)l * 16] = tv[slot];
  };

#define BRD(i) (*(const h8*)&buf[(size_t)(fb2 + (i)) * 1024 + (size_t)l * 16])

  auto consume = [&](int cs, const char* buf) {
    int fb2 = 0;
#pragma unroll
    for (int tt = 0; tt < 4; ++tt) {
      if (cs + tt >= tEnd) continue;
      const int kt = cs + tt;
      const int rt_ = rtab[kt * 4 + g];
      const int oA_ = rt_ & 31, oB_ = (rt_ >> 5) & 31, jb_ = (rt_ >> 10) & 1;
      const float xab0 = xT[0][ch][oA_] * xT[0][ch][oB_];
      const float xab1 = xT[1][ch][oA_] * xT[1][ch][oB_];
      const _Float16 hm0 = (_Float16)xab0, hm1 = (_Float16)xab1;   // RTE
      const h8 m0 = {hm0, hm0, hm0, hm0, hm0, hm0, hm0, hm0};
      const h8 m1 = {hm1, hm1, hm1, hm1, hm1, hm1, hm1, hm1};
      const h8 af0 = m0 * (jb_ ? xh0h : xh0l);   // 4x v_pk_mul_f16
      const h8 af1 = m1 * (jb_ ? xh1h : xh1l);
      if (kt < 43) {
        h8 b0 = BRD(0), b1 = BRD(1), b2 = BRD(2), b3 = BRD(3), b4 = BRD(4), b5 = BRD(5), b6 = BRD(6);
        acc[0][0] = MFMA16(af0, b0, acc[0][0]); acc[1][0] = MFMA16(af1, b0, acc[1][0]);
        acc[0][1] = MFMA16(af0, b1, acc[0][1]); acc[1][1] = MFMA16(af1, b1, acc[1][1]);
        acc[0][2] = MFMA16(af0, b2, acc[0][2]); acc[1][2] = MFMA16(af1, b2, acc[1][2]);
        acc[0][3] = MFMA16(af0, b3, acc[0][3]); acc[1][3] = MFMA16(af1, b3, acc[1][3]);
        acc[0][4] = MFMA16(af0, b4, acc[0][4]); acc[1][4] = MFMA16(af1, b4, acc[1][4]);
        acc[0][5] = MFMA16(af0, b5, acc[0][5]); acc[1][5] = MFMA16(af1, b5, acc[1][5]);
        acc[0][6] = MFMA16(af0, b6, acc[0][6]); acc[1][6] = MFMA16(af1, b6, acc[1][6]);
        fb2 += 7;
      } else if (kt < 49) {
        h8 b0 = BRD(0), b1 = BRD(1), b2 = BRD(2);
        acc[0][7] = MFMA16(af0, b0, acc[0][7]); acc[1][7] = MFMA16(af1, b0, acc[1][7]);
        acc[0][8] = MFMA16(af0, b1, acc[0][8]); acc[1][8] = MFMA16(af1, b1, acc[1][8]);
        acc[0][9] = MFMA16(af0, b2, acc[0][9]); acc[1][9] = MFMA16(af1, b2, acc[1][9]);
        fb2 += 3;
      } else {
        h8 b0 = BRD(0);
        acc[0][10] = MFMA16(af0, b0, acc[0][10]); acc[1][10] = MFMA16(af1, b0, acc[1][10]);
        fb2 += 1;
      }
    }
  };

  // ---- pipelined main loop: chunks of 4 tiles; 1 barrier/chunk ----
  issue(T0);
  __syncthreads();           // xT/rtab visible
  wr(bs[0]);
  __syncthreads();
#pragma unroll 1
  for (int ck = 0; ck < nck; ++ck) {
    const int cs = T0 + ck * 4;
    if (ck + 1 < nck) issue(cs + 4);
    consume(cs, bs[ck & 1]);
    if (ck + 1 < nck) {
      wr(bs[(ck & 1) ^ 1]);   // that buffer was consumed a chunk ago, barrier-separated
      __syncthreads();
    }
  }

  // ---- species fold -> f32 partials in ws[ksp][n][o][c] (plain stores, no atomics) ----
  {
    const int o = l & 15;
    int ir, ii; o_to_iri(o, ir, ii); (void)ii;
    const int cb = w * 16 + g * 4;
#pragma unroll
    for (int p = 0; p < 2; ++p) {
      const int sp = p ? s1 : s0;
      float tot[4] = {0.f, 0.f, 0.f, 0.f};
#pragma unroll
      for (int k = 0; k < 7; ++k) {
        const float4 wv = *(const float4*)(w3 + ((size_t)(ir * S_SPEC + sp) * 7 + k) * C_CH + cb);
        tot[0] = fmaf(wv.x, acc[p][k][0], tot[0]);
        tot[1] = fmaf(wv.y, acc[p][k][1], tot[1]);
        tot[2] = fmaf(wv.z, acc[p][k][2], tot[2]);
        tot[3] = fmaf(wv.w, acc[p][k][3], tot[3]);
      }
#pragma unroll
      for (int k = 0; k < 3; ++k) {
        const float4 wv = *(const float4*)(w2 + ((size_t)(ir * S_SPEC + sp) * 3 + k) * C_CH + cb);
        tot[0] = fmaf(wv.x, acc[p][7 + k][0], tot[0]);
        tot[1] = fmaf(wv.y, acc[p][7 + k][1], tot[1]);
        tot[2] = fmaf(wv.z, acc[p][7 + k][2], tot[2]);
        tot[3] = fmaf(wv.w, acc[p][7 + k][3], tot[3]);
      }
      {
        const float4 wv = *(const float4*)(w1 + (size_t)(ir * S_SPEC + sp) * C_CH + cb);
        tot[0] = fmaf(wv.x, acc[p][10][0], tot[0]);
        tot[1] = fmaf(wv.y, acc[p][10][1], tot[1]);
        tot[2] = fmaf(wv.z, acc[p][10][2], tot[2]);
        tot[3] = fmaf(wv.w, acc[p][10][3], tot[3]);
      }
      float4 st = {tot[0], tot[1], tot[2], tot[3]};
      *(float4*)(ws + (((size_t)ksp * N_NODES + (n0 + p)) * 16 + o) * C_CH + cb) = st;
    }
  }
}

// ---------------- finisher: sum K-halves, build Ef, wlin MFMA, store out ----------------

__global__ __launch_bounds__(256) void eqp_fin(
    const float* __restrict__ ws, float* __restrict__ out, int nsp) {
  __shared__ _Float16 Ef[8192];   // [ks16][lg4][o16][i8] = 16 KB
  const int t = threadIdx.x;
  const int l = t & 63;
  const int w = t >> 6;
  const int n = blockIdx.x;

  {  // zero Ef (other-ir slots must be 0)
    float4* z = (float4*)Ef;
    z[t] = (float4){0.f, 0.f, 0.f, 0.f};
    z[t + 256] = (float4){0.f, 0.f, 0.f, 0.f};
    z[t + 512] = (float4){0.f, 0.f, 0.f, 0.f};
    z[t + 768] = (float4){0.f, 0.f, 0.f, 0.f};
  }
  __syncthreads();

  {  // load both partials, sum, scatter to Ef (fp16)
    const float4* p0 = (const float4*)(ws + (size_t)n * 2048);
    const float4* p1 = (const float4*)(ws + ((size_t)N_NODES + n) * 2048);
#pragma unroll
    for (int q = 0; q < 2; ++q) {
      const int off = t + q * 256;           // float4 index: o = off>>5, c = (off&31)*4..
      float4 a = p0[off];
      if (nsp == 2) {
        const float4 b = p1[off];
        a.x += b.x; a.y += b.y; a.z += b.z; a.w += b.w;
      }
      const int o = off >> 5;
      const int cbase = (off & 31) * 4;
      int ir, ii; o_to_iri(o, ir, ii); (void)ii;
      const float av[4] = {a.x, a.y, a.z, a.w};
#pragma unroll
      for (int r = 0; r < 4; ++r) {
        const int k = ir * 128 + cbase + r;
        Ef[((((k >> 5) * 4) + ((k >> 3) & 3)) * 16 + o) * 8 + (k & 7)] = (_Float16)av[r];
      }
    }
  }
  __syncthreads();

  // wlin channel mix via MFMA: wave w handles M-tiles w and w+4
  const int dis[4]  = {1, 3, 5, 7};
  const int ooff[4] = {0, 128, 512, 1152};
#pragma unroll
  for (int mi = 0; mi < 2; ++mi) {
    const int mt = w + mi * 4;
    f32x4 D = {0.f, 0.f, 0.f, 0.f};
#pragma unroll
    for (int ks = 0; ks < 16; ++ks) {
      const h8 aw = g_Wf[(mt * 16 + ks) * 64 + l];
      const h8 b = *(const h8*)&Ef[((ks * 4 + (l >> 4)) * 16 + (l & 15)) * 8];
      D = MFMA16(aw, b, D);
    }
    const int o = l & 15;
    int ir, ii; o_to_iri(o, ir, ii);
    const size_t base = (size_t)n * 2048 + ooff[ir] + ii;
#pragma unroll
    for (int r = 0; r < 4; ++r) {
      const int f = mt * 16 + (l >> 4) * 4 + r;
      out[base + (size_t)f * dis[ir]] = D[r];
    }
  }
}

// ---------------- launch ----------------

extern "C" void kernel_launch(void* const* d_in, const int* in_sizes, int n_in,
                              void* d_out, int out_size, void* d_ws, size_t ws_size,
                              hipStream_t stream) {
  const float* x      = (const float*)d_in[0];
  const int*   specie = (const int*)d_in[1];

  const float *u1s[4], *u2s[4], *u3s[4];
  if (in_sizes[3] == 768) {  // interleaved dict order: u1_0,u2_0,u3_0,u1_1,...
    for (int i = 0; i < 4; ++i) {
      u1s[i] = (const float*)d_in[2 + 3 * i];
      u2s[i] = (const float*)d_in[3 + 3 * i];
      u3s[i] = (const float*)d_in[4 + 3 * i];
    }
  } else {                   // grouped order: u1_0..u1_3,u2_0..u2_3,u3_0..u3_3
    for (int i = 0; i < 4; ++i) {
      u1s[i] = (const float*)d_in[2 + i];
      u2s[i] = (const float*)d_in[6 + i];
      u3s[i] = (const float*)d_in[10 + i];
    }
  }
  const float* w1   = (const float*)d_in[14];
  const float* w2   = (const float*)d_in[15];
  const float* w3   = (const float*)d_in[16];
  const float* wlin = (const float*)d_in[17];
  float* out = (float*)d_out;
  float* ws  = (float*)d_ws;
  (void)out_size; (void)n_in;

  const size_t need2 = 2ull * N_NODES * 2048 * sizeof(float);
  const int nsp = (ws_size >= need2) ? 2 : 1;

  build_all<<<448, 64, 0, stream>>>(
      u1s[0], u1s[1], u1s[2], u1s[3],
      u2s[0], u2s[1], u2s[2], u2s[3],
      u3s[0], u3s[1], u3s[2], u3s[3], wlin);
  eqp_mm<<<dim3(N_NODES / 2, nsp), 512, 0, stream>>>(x, specie, w1, w2, w3, ws, nsp);
  eqp_fin<<<N_NODES, 256, 0, stream>>>(ws, out, nsp);
}

// Round 13
// 71.817 us; speedup vs baseline: 1.3122x; 1.3122x over previous
//
#include <hip/hip_runtime.h>

#define N_NODES 512
#define C_CH    128
#define S_SPEC  10
#define KT      50
#define NT      11

typedef _Float16 h8 __attribute__((ext_vector_type(8)));
typedef float f32x4 __attribute__((ext_vector_type(4)));

// K layout: 50 tiles x 32 slots; tile = 4 octets (one per lane-group g).
// Octet = (offA, offB, j0): slot i computes x[offA]*x[offB]*x[j0+i], j0 in {0,8}.
// N cols (o-major): nt 0..6 = k3, 7..9 = k2, 10 = k1; col = o (0..15).
__device__ h8 g_Bf[KT * NT * 64];   // B pre-swizzled to MFMA B-frag order [kt][nt][lane]
__device__ h8 g_Wf[128 * 64];       // wlin as A-frags: [mt*16+ks][lane], K-expanded (ir,cc)

__device__ __forceinline__ void o_to_iri(int o, int& ir, int& i) {
  if (o >= 9)      { ir = 3; i = o - 9; }
  else if (o >= 4) { ir = 2; i = o - 4; }
  else if (o >= 1) { ir = 1; i = o - 1; }
  else             { ir = 0; i = 0; }
}

__device__ int octet_desc(int Q) {
  if (Q < 172) {                     // order-3
    int q = Q;
    for (int a = 0; a < 16; ++a)
      for (int b = a; b < 16; ++b) {
        int no = (b < 8) ? 2 : 1;
        if (q < no) {
          int jb = (no == 1) ? 1 : q;          // b<8: q0->j0=0,q1->j0=8; b>=8: j0=8
          return a | (b << 5) | (jb << 10);
        }
        q -= no;
      }
  } else if (Q < 196) {              // order-2
    int q = Q - 172;
    for (int a = 0; a < 16; ++a) {
      int no = (a < 8) ? 2 : 1;
      if (q < no) {
        int jb = (no == 1) ? 1 : q;
        return a | (16 << 5) | (jb << 10);
      }
      q -= no;
    }
  } else if (Q < 198) {              // order-1
    return 16 | (16 << 5) | ((Q - 196) << 10);
  }
  return 17 | (17 << 5);             // pad (zero column)
}

// ---- merged build: virtual bids 0..319 build B fragments, 320..447 build W fragments ----
__global__ void build_all(const float* __restrict__ u1_0, const float* __restrict__ u1_1,
                          const float* __restrict__ u1_2, const float* __restrict__ u1_3,
                          const float* __restrict__ u2_0, const float* __restrict__ u2_1,
                          const float* __restrict__ u2_2, const float* __restrict__ u2_3,
                          const float* __restrict__ u3_0, const float* __restrict__ u3_1,
                          const float* __restrict__ u3_2, const float* __restrict__ u3_3,
                          const float* __restrict__ wlin) {
  const int id  = blockIdx.x * 256 + threadIdx.x;   // 112*256 = 448*64
  const int bid = id >> 6;
  const int l   = id & 63;
  const int dis[4] = {1, 3, 5, 7};
  if (bid < 320) {
    int kt, nt;
    if (bid < 301)      { kt = bid / 7; nt = bid % 7; }
    else if (bid < 319) { int e = bid - 301; kt = 43 + e / 3; nt = 7 + e % 3; }
    else                { kt = 49; nt = 10; }

    const int o = l & 15;
    int ir, ii; o_to_iri(o, ir, ii);
    const int di = dis[ir];
    const float* u1s[4] = {u1_0, u1_1, u1_2, u1_3};
    const float* u2s[4] = {u2_0, u2_1, u2_2, u2_3};
    const float* u3s[4] = {u3_0, u3_1, u3_2, u3_3};

    const int rt = octet_desc(kt * 4 + (l >> 4));
    const int oA = rt & 31, oB = (rt >> 5) & 31, j0 = ((rt >> 10) & 1) * 8;

    h8 v;
#pragma unroll
    for (int i = 0; i < 8; ++i) {
      const int j = j0 + i;
      float val = 0.f;
      if (oA < 16 && oB < 16) {              // order-3, canonical a<=b<=j
        if (j >= oB) {
          const float* u = u3s[ir];
          int a = oA, b = oB;
          int P[6][3] = {{a,b,j},{a,j,b},{b,a,j},{b,j,a},{j,a,b},{j,b,a}};
          for (int p = 0; p < 6; ++p) {
            bool dup = false;
            for (int r = 0; r < p; ++r)
              if (P[r][0] == P[p][0] && P[r][1] == P[p][1] && P[r][2] == P[p][2]) { dup = true; break; }
            if (!dup)
              val += u[(((P[p][0] * 16 + P[p][1]) * 16 + P[p][2]) * 7 + nt) * di + ii];
          }
        }
      } else if (oA < 16 && oB == 16) {      // order-2 (oA <= j)
        if (j >= oA) {
          const int k2 = nt - 7;
          const float* u = u2s[ir];
          val = u[((oA * 16 + j) * 3 + k2) * di + ii];
          if (j != oA) val += u[((j * 16 + oA) * 3 + k2) * di + ii];
        }
      } else if (oA == 16) {                 // order-1
        val = u1s[ir][j * di + ii];
      }
      v[i] = (_Float16)val;
    }
    g_Bf[((size_t)kt * NT + nt) * 64 + l] = v;
  } else {
    // wlin -> fp16 A-frags over expanded K = (ir*128+cc), scaled by 1/sqrt(128)
    const int idW = (bid - 320) * 64 + l;    // 8192 total
    const int ks = (idW >> 6) & 15, mt = idW >> 10;
    const int f = mt * 16 + (l & 15);
    const float inv = 0.08838834764831845f;
    h8 v;
#pragma unroll
    for (int i = 0; i < 8; ++i) {
      const int k = ks * 32 + (l >> 4) * 8 + i;
      const int ir = k >> 7, cc = k & 127;
      v[i] = (_Float16)(wlin[((size_t)ir * C_CH + cc) * C_CH + f] * inv);
    }
    g_Wf[(mt * 16 + ks) * 64 + l] = v;
  }
}

// ---------------- main kernel: 4 nodes/block (r=4), K-split, early small-fold ----------------
// NOTE: no min-waves in __launch_bounds__ (R1/R4/R8 spilled when capped).
// LDS ~95.6 KB -> 1 block/CU by design; grid (128, nsp) = 256 blocks = 1/CU.

#define MFMA16(A, B, C) __builtin_amdgcn_mfma_f32_16x16x32_f16(A, B, C, 0, 0, 0)

__global__ __launch_bounds__(512, 1) void eqp_mm(
    const float* __restrict__ x, const int* __restrict__ specie,
    const float* __restrict__ w1, const float* __restrict__ w2,
    const float* __restrict__ w3, float* __restrict__ ws, int nsp) {
  __shared__ __align__(16) char bs0[28 * 1024];
  __shared__ __align__(16) char bs1[28 * 1024];
  __shared__ float xv[18][4][130];    // j-major: [j 0..15, 16=ones, 17=zeros][node][ch padded]
  __shared__ int rtab[KT * 4];

  const int t = threadIdx.x;
  const int l = t & 63;
  const int w = t >> 6;
  const int g = l >> 4;
  const int n0 = blockIdx.x * 4;
  const int ksp = blockIdx.y;
  const bool doSmall = (nsp == 1) || (ksp == 1);
  const int T0   = (nsp == 2 && ksp == 1) ? 22 : 0;
  const int tEnd = (nsp == 2 && ksp == 0) ? 22 : 43;

  {  // stage xv (transposed, j-major) + rtab
    const int p = t >> 7, c = t & 127;
    const float4* xp = (const float4*)(x + ((size_t)(n0 + p) * C_CH + c) * 16);
    const float4 v0 = xp[0], v1 = xp[1], v2 = xp[2], v3 = xp[3];
    const float vs[16] = {v0.x, v0.y, v0.z, v0.w, v1.x, v1.y, v1.z, v1.w,
                          v2.x, v2.y, v2.z, v2.w, v3.x, v3.y, v3.z, v3.w};
#pragma unroll
    for (int j = 0; j < 16; ++j) xv[j][p][c] = vs[j];
    xv[16][p][c] = 1.f;
    xv[17][p][c] = 0.f;
    if (t < KT * 4) rtab[t] = octet_desc(t);
  }

  const int ch = w * 16 + (l & 15);
  int sp4[4];
#pragma unroll
  for (int p = 0; p < 4; ++p) sp4[p] = specie[n0 + p];

  // packed fp16 x registers per node (RTE), j-octets
  auto packh = [](float4 u, float4 v) {
    h8 r;
    r[0] = (_Float16)u.x; r[1] = (_Float16)u.y; r[2] = (_Float16)u.z; r[3] = (_Float16)u.w;
    r[4] = (_Float16)v.x; r[5] = (_Float16)v.y; r[6] = (_Float16)v.z; r[7] = (_Float16)v.w;
    return r;
  };
  h8 xh[4][2];
#pragma unroll
  for (int p = 0; p < 4; ++p) {
    const float4* pp = (const float4*)(x + ((size_t)(n0 + p) * C_CH + ch) * 16);
    xh[p][0] = packh(pp[0], pp[1]);
    xh[p][1] = packh(pp[2], pp[3]);
  }

  f32x4 a3[4][7];
#pragma unroll
  for (int p = 0; p < 4; ++p)
#pragma unroll
    for (int k = 0; k < 7; ++k) a3[p][k] = (f32x4){0.f, 0.f, 0.f, 0.f};
  f32x4 pt[4];
#pragma unroll
  for (int p = 0; p < 4; ++p) pt[p] = (f32x4){0.f, 0.f, 0.f, 0.f};

  h8 tv[4]; int dst[4];

  // A-fragment generation for all 4 nodes from xv (read2-pair loads) + xh pk-mul
  auto afgen = [&](int rt_, h8* af) {
    const int oA = rt_ & 31, oB = (rt_ >> 5) & 31, jb = (rt_ >> 10) & 1;
    const float* pa = &xv[oA][0][ch];
    const float* pb = &xv[oB][0][ch];
    const float a0 = pa[0], a1 = pa[130], a2 = pa[260], a3v = pa[390];
    const float b0 = pb[0], b1 = pb[130], b2 = pb[260], b3v = pb[390];
    const float m[4] = {a0 * b0, a1 * b1, a2 * b2, a3v * b3v};
#pragma unroll
    for (int p = 0; p < 4; ++p) {
      const _Float16 hm = (_Float16)m[p];
      const h8 mv = {hm, hm, hm, hm, hm, hm, hm, hm};
      af[p] = mv * (jb ? xh[p][1] : xh[p][0]);
    }
  };

  auto issue_small = [&]() {
#pragma unroll
    for (int s2 = 0; s2 < 3; ++s2) {
      const int fi = s2 * 8 + w;
      const bool ok = fi < 19;
      int kt = 43 + fi / 3, nt = 7 + fi % 3;
      if (fi == 18) { kt = 49; nt = 10; }
      dst[s2] = ok ? fi : -1;
      if (ok) tv[s2] = g_Bf[((size_t)kt * NT + nt) * 64 + l];
    }
    dst[3] = -1;
  };
  auto issue_o3 = [&](int cs) {
    const int rem = tEnd - cs;
    const int nf = (rem < 4 ? rem : 4) * 7;
#pragma unroll
    for (int s2 = 0; s2 < 4; ++s2) {
      const int fi = s2 * 8 + w;
      const bool ok = fi < nf;
      dst[s2] = ok ? fi : -1;
      if (ok) {
        const int kt = cs + fi / 7, nt = fi % 7;
        tv[s2] = g_Bf[((size_t)kt * NT + nt) * 64 + l];
      }
    }
  };
  auto wr = [&](char* buf) {
#pragma unroll
    for (int s2 = 0; s2 < 4; ++s2)
      if (dst[s2] >= 0) *(h8*)&buf[(size_t)dst[s2] * 1024 + (size_t)l * 16] = tv[s2];
  };

  auto consume_o3 = [&](int cs, const char* buf) {
#pragma unroll
    for (int tt = 0; tt < 4; ++tt) {
      if (cs + tt >= tEnd) continue;
      const int kt = cs + tt;
      h8 af[4];
      afgen(rtab[kt * 4 + g], af);
#pragma unroll
      for (int nt = 0; nt < 7; ++nt) {
        const h8 b = *(const h8*)&buf[(size_t)(tt * 7 + nt) * 1024 + (size_t)l * 16];
        a3[0][nt] = MFMA16(af[0], b, a3[0][nt]);
        a3[1][nt] = MFMA16(af[1], b, a3[1][nt]);
        a3[2][nt] = MFMA16(af[2], b, a3[2][nt]);
        a3[3][nt] = MFMA16(af[3], b, a3[3][nt]);
      }
    }
  };

  // small phase: order-2 (tiles 43..48) + order-1 (49), folded immediately into pt
  auto small_phase = [&](const char* buf) {
    f32x4 a2[4][3], a1v[4];
#pragma unroll
    for (int p = 0; p < 4; ++p) {
#pragma unroll
      for (int k = 0; k < 3; ++k) a2[p][k] = (f32x4){0.f, 0.f, 0.f, 0.f};
      a1v[p] = (f32x4){0.f, 0.f, 0.f, 0.f};
    }
#pragma unroll
    for (int i = 0; i < 6; ++i) {
      h8 af[4];
      afgen(rtab[(43 + i) * 4 + g], af);
#pragma unroll
      for (int k = 0; k < 3; ++k) {
        const h8 b = *(const h8*)&buf[(size_t)(i * 3 + k) * 1024 + (size_t)l * 16];
        a2[0][k] = MFMA16(af[0], b, a2[0][k]);
        a2[1][k] = MFMA16(af[1], b, a2[1][k]);
        a2[2][k] = MFMA16(af[2], b, a2[2][k]);
        a2[3][k] = MFMA16(af[3], b, a2[3][k]);
      }
    }
    {
      h8 af[4];
      afgen(rtab[49 * 4 + g], af);
      const h8 b = *(const h8*)&buf[(size_t)18 * 1024 + (size_t)l * 16];
      a1v[0] = MFMA16(af[0], b, a1v[0]);
      a1v[1] = MFMA16(af[1], b, a1v[1]);
      a1v[2] = MFMA16(af[2], b, a1v[2]);
      a1v[3] = MFMA16(af[3], b, a1v[3]);
    }
    const int o = l & 15;
    int ir, ii; o_to_iri(o, ir, ii); (void)ii;
    const int cb = w * 16 + g * 4;
#pragma unroll
    for (int p = 0; p < 4; ++p) {
      const int sp = sp4[p];
      f32x4 tot = {0.f, 0.f, 0.f, 0.f};
#pragma unroll
      for (int k = 0; k < 3; ++k) {
        const float4 wv = *(const float4*)(w2 + ((size_t)(ir * S_SPEC + sp) * 3 + k) * C_CH + cb);
        tot[0] = fmaf(wv.x, a2[p][k][0], tot[0]);
        tot[1] = fmaf(wv.y, a2[p][k][1], tot[1]);
        tot[2] = fmaf(wv.z, a2[p][k][2], tot[2]);
        tot[3] = fmaf(wv.w, a2[p][k][3], tot[3]);
      }
      {
        const float4 wv = *(const float4*)(w1 + (size_t)(ir * S_SPEC + sp) * C_CH + cb);
        tot[0] = fmaf(wv.x, a1v[p][0], tot[0]);
        tot[1] = fmaf(wv.y, a1v[p][1], tot[1]);
        tot[2] = fmaf(wv.z, a1v[p][2], tot[2]);
        tot[3] = fmaf(wv.w, a1v[p][3], tot[3]);
      }
      pt[p] = tot;
    }
  };

  // ---- prologue + pipelined main loop ----
  if (doSmall) issue_small();
  __syncthreads();                 // xv/rtab visible
  if (doSmall) {
    wr(bs0);                       // small chunk -> bs0
    issue_o3(T0);                  // overlap chunk0 loads with small consume
    __syncthreads();               // bs0 visible
    small_phase(bs0);
  } else {
    issue_o3(T0);
  }
  wr(bs1);                         // chunk0 -> bs1
  __syncthreads();

  const int nck = (tEnd - T0 + 3) / 4;
#pragma unroll 1
  for (int ck = 0; ck < nck; ++ck) {
    const int cs = T0 + ck * 4;
    if (ck + 1 < nck) issue_o3(cs + 4);
    consume_o3(cs, (ck & 1) ? bs0 : bs1);
    if (ck + 1 < nck) {
      wr((ck & 1) ? bs1 : bs0);    // last read a chunk ago, barrier-separated
      __syncthreads();
    }
  }

  // ---- epilogue: w3-fold + pt, store f32 partials to ws (plain stores) ----
  {
    const int o = l & 15;
    int ir, ii; o_to_iri(o, ir, ii); (void)ii;
    const int cb = w * 16 + g * 4;
#pragma unroll
    for (int p = 0; p < 4; ++p) {
      const int sp = sp4[p];
      f32x4 tot = pt[p];
#pragma unroll
      for (int k = 0; k < 7; ++k) {
        const float4 wv = *(const float4*)(w3 + ((size_t)(ir * S_SPEC + sp) * 7 + k) * C_CH + cb);
        tot[0] = fmaf(wv.x, a3[p][k][0], tot[0]);
        tot[1] = fmaf(wv.y, a3[p][k][1], tot[1]);
        tot[2] = fmaf(wv.z, a3[p][k][2], tot[2]);
        tot[3] = fmaf(wv.w, a3[p][k][3], tot[3]);
      }
      float4 st = {tot[0], tot[1], tot[2], tot[3]};
      *(float4*)(ws + (((size_t)ksp * N_NODES + (n0 + p)) * 16 + o) * C_CH + cb) = st;
    }
  }
}

// ---------------- finisher: sum K-parts, build Ef, wlin MFMA, store out ----------------

__global__ __launch_bounds__(256) void eqp_fin(
    const float* __restrict__ ws, float* __restrict__ out, int nsp) {
  __shared__ _Float16 Ef[8192];   // [ks16][lg4][o16][i8] = 16 KB
  const int t = threadIdx.x;
  const int l = t & 63;
  const int w = t >> 6;
  const int n = blockIdx.x;

  {  // zero Ef (other-ir slots must be 0)
    float4* z = (float4*)Ef;
    z[t] = (float4){0.f, 0.f, 0.f, 0.f};
    z[t + 256] = (float4){0.f, 0.f, 0.f, 0.f};
    z[t + 512] = (float4){0.f, 0.f, 0.f, 0.f};
    z[t + 768] = (float4){0.f, 0.f, 0.f, 0.f};
  }
  __syncthreads();

  {  // load partials, sum, scatter to Ef (fp16)
    const float4* p0 = (const float4*)(ws + (size_t)n * 2048);
    const float4* p1 = (const float4*)(ws + ((size_t)N_NODES + n) * 2048);
#pragma unroll
    for (int q = 0; q < 2; ++q) {
      const int off = t + q * 256;           // float4 index: o = off>>5, c = (off&31)*4..
      float4 a = p0[off];
      if (nsp == 2) {
        const float4 b = p1[off];
        a.x += b.x; a.y += b.y; a.z += b.z; a.w += b.w;
      }
      const int o = off >> 5;
      const int cbase = (off & 31) * 4;
      int ir, ii; o_to_iri(o, ir, ii); (void)ii;
      const float av[4] = {a.x, a.y, a.z, a.w};
#pragma unroll
      for (int r = 0; r < 4; ++r) {
        const int k = ir * 128 + cbase + r;
        Ef[((((k >> 5) * 4) + ((k >> 3) & 3)) * 16 + o) * 8 + (k & 7)] = (_Float16)av[r];
      }
    }
  }
  __syncthreads();

  // wlin channel mix via MFMA: wave w handles M-tiles w and w+4
  const int dis[4]  = {1, 3, 5, 7};
  const int ooff[4] = {0, 128, 512, 1152};
#pragma unroll
  for (int mi = 0; mi < 2; ++mi) {
    const int mt = w + mi * 4;
    f32x4 D = {0.f, 0.f, 0.f, 0.f};
#pragma unroll
    for (int ks = 0; ks < 16; ++ks) {
      const h8 aw = g_Wf[(mt * 16 + ks) * 64 + l];
      const h8 b = *(const h8*)&Ef[((ks * 4 + (l >> 4)) * 16 + (l & 15)) * 8];
      D = MFMA16(aw, b, D);
    }
    const int o = l & 15;
    int ir, ii; o_to_iri(o, ir, ii);
    const size_t base = (size_t)n * 2048 + ooff[ir] + ii;
#pragma unroll
    for (int r = 0; r < 4; ++r) {
      const int f = mt * 16 + (l >> 4) * 4 + r;
      out[base + (size_t)f * dis[ir]] = D[r];
    }
  }
}

// ---------------- launch ----------------

extern "C" void kernel_launch(void* const* d_in, const int* in_sizes, int n_in,
                              void* d_out, int out_size, void* d_ws, size_t ws_size,
                              hipStream_t stream) {
  const float* x      = (const float*)d_in[0];
  const int*   specie = (const int*)d_in[1];

  const float *u1s[4], *u2s[4], *u3s[4];
  if (in_sizes[3] == 768) {  // interleaved dict order: u1_0,u2_0,u3_0,u1_1,...
    for (int i = 0; i < 4; ++i) {
      u1s[i] = (const float*)d_in[2 + 3 * i];
      u2s[i] = (const float*)d_in[3 + 3 * i];
      u3s[i] = (const float*)d_in[4 + 3 * i];
    }
  } else {                   // grouped order: u1_0..u1_3,u2_0..u2_3,u3_0..u3_3
    for (int i = 0; i < 4; ++i) {
      u1s[i] = (const float*)d_in[2 + i];
      u2s[i] = (const float*)d_in[6 + i];
      u3s[i] = (const float*)d_in[10 + i];
    }
  }
  const float* w1   = (const float*)d_in[14];
  const float* w2   = (const float*)d_in[15];
  const float* w3   = (const float*)d_in[16];
  const float* wlin = (const float*)d_in[17];
  float* out = (float*)d_out;
  float* ws  = (float*)d_ws;
  (void)out_size; (void)n_in;

  const size_t need2 = 2ull * N_NODES * 2048 * sizeof(float);
  const int nsp = (ws_size >= need2) ? 2 : 1;

  build_all<<<112, 256, 0, stream>>>(
      u1s[0], u1s[1], u1s[2], u1s[3],
      u2s[0], u2s[1], u2s[2], u2s[3],
      u3s[0], u3s[1], u3s[2], u3s[3], wlin);
  eqp_mm<<<dim3(N_NODES / 4, nsp), 512, 0, stream>>>(x, specie, w1, w2, w3, ws, nsp);
  eqp_fin<<<N_NODES, 256, 0, stream>>>(ws, out, nsp);
}